// Round 14
// baseline (355.764 us; speedup 1.0000x reference)
//
#include <hip/hip_runtime.h>

// ---------------------------------------------------------------------------
// CrossAttentionMM on MI355X (gfx950), bf16 MFMA pipeline.
// B=4, SQ=4096, SKV=1024, QDIM=1024, CDIM=768, H=16, D=64, INNER=1024.
// R19: MEASUREMENT ROUND. attn split into two half-grid dispatches (~58us
// each) so the GEMMs/prep finally surface in the top-5 counter table —
// 13 rounds of GEMM work have been blind (attn's 115us flooded all slots;
// 2 different GEMM structures gave identical totals; binding factor unknown).
// Everything else identical to the best config (R16, 342us): 256^2 8-phase
// GEMMs + coalesced swizzled staging + XCD swizzle; attn v9 (R14 body, R18's
// null 2-deep pipeline dropped); fused prep.
// ---------------------------------------------------------------------------

typedef unsigned short u16;
typedef unsigned int u32;
typedef __bf16 bf16x8 __attribute__((ext_vector_type(8)));
typedef float float4v __attribute__((ext_vector_type(4)));
typedef _Float16 half4 __attribute__((ext_vector_type(4)));
typedef _Float16 half2v __attribute__((ext_vector_type(2)));
typedef __attribute__((address_space(1))) void as1_void;
typedef __attribute__((address_space(3))) void as3_void;

__device__ __forceinline__ u16 f2bf(float f) {
  unsigned u = __float_as_uint(f);
  u += 0x7FFF + ((u >> 16) & 1);   // RTNE
  return (u16)(u >> 16);
}

// async global->LDS, 16B per lane. LDS dest = wave-uniform base + lane*16.
__device__ __forceinline__ void async16(const u16* g, u16* l) {
  __builtin_amdgcn_global_load_lds((as1_void*)(void*)g, (as3_void*)l, 16, 0, 0);
}

// gfx9 waitcnt imm: vmcnt[3:0]=imm[3:0], exp=imm[6:4], lgkm=imm[11:8], vmcnt[5:4]=imm[15:14]
#define WAITCNT_VM8 0xF78   // vmcnt(8), lgkm/exp no-wait
#define WAITCNT_VM4 0xF74   // vmcnt(4)
#define WAITCNT_VM0 0xF70   // vmcnt(0)

// ---------------- fused prep: fp32->bf16 casts + all 4 weight transposes ---
// blocks [0,19456): cvt of x then ctx (float4 per thread)
// blocks [19456,23552): twt — z=(b-19456)>>10, 32x32 tile transpose via LDS
__global__ void prep_kernel(const float* __restrict__ x, u16* __restrict__ xbf,
                            const float* __restrict__ ctx, u16* __restrict__ ctxbf,
                            const float* __restrict__ Wq, const float* __restrict__ Wk,
                            const float* __restrict__ Wv, const float* __restrict__ Wo,
                            u16* __restrict__ WqT, u16* __restrict__ WkT,
                            u16* __restrict__ WvT, u16* __restrict__ WoT) {
  __shared__ u16 t[32][33];
  int blk = blockIdx.x;
  if (blk < 19456) {
    int i = blk * 256 + threadIdx.x;
    const float* in; u16* out; int j;
    if (i < 4194304) { in = x; out = xbf; j = i; }
    else if (i < 4980736) { in = ctx; out = ctxbf; j = i - 4194304; }
    else return;
    float4 v = ((const float4*)in)[j];
    ushort4 o;
    o.x = f2bf(v.x); o.y = f2bf(v.y); o.z = f2bf(v.z); o.w = f2bf(v.w);
    ((ushort4*)out)[j] = o;
    return;
  }
  int rem = blk - 19456;
  int z = rem >> 10, r1 = rem & 1023;
  int by = r1 >> 5, bxx = r1 & 31;
  const float* W = z == 0 ? Wq : z == 1 ? Wk : z == 2 ? Wv : Wo;
  u16* Wt = z == 0 ? WqT : z == 1 ? WkT : z == 2 ? WvT : WoT;
  int Kd = (z == 1 || z == 2) ? 768 : 1024;
  int k0 = by * 32;
  if (k0 >= Kd) return;
  int tid = threadIdx.x;
  int tx = tid & 31, ty = tid >> 5;
  int n0 = bxx * 32;
#pragma unroll
  for (int i = 0; i < 4; i++)
    t[ty + i * 8][tx] = f2bf(W[(size_t)(k0 + ty + i * 8) * 1024 + n0 + tx]);
  __syncthreads();
#pragma unroll
  for (int i = 0; i < 4; i++)
    Wt[(size_t)(n0 + ty + i * 8) * Kd + k0 + tx] = t[tx][ty + i * 8];
}

// ---------------------------------------------------------------------------
// 256x256 / BK=64 / 8-wave 8-phase GEMM core (C = A * Bt^T), bf16 inputs.
// LDS: [buf][A/B][row(256)][k(64)] bf16, 3-bit XOR chunk swizzle per row.
// ---------------------------------------------------------------------------

__device__ __forceinline__ void ld_a4(const u16* Lp, int rbase, int quad,
                                      int l15, bf16x8 a[4][2]) {
  int lb = l15 & 7;
  const char* base = (const char*)Lp;
#pragma unroll
  for (int mi = 0; mi < 4; mi++)
#pragma unroll
    for (int ks = 0; ks < 2; ks++)
      a[mi][ks] = *(const bf16x8*)(base + (rbase + mi * 16 + l15) * 128 +
                                   (((ks * 4 + quad) ^ lb) << 4));
}

__device__ __forceinline__ void ld_b2(const u16* Lp, int rbase, int quad,
                                      int l15, bf16x8 b[2][2]) {
  int lb = l15 & 7;
  const char* base = (const char*)Lp;
#pragma unroll
  for (int ni = 0; ni < 2; ni++)
#pragma unroll
    for (int ks = 0; ks < 2; ks++)
      b[ni][ks] = *(const bf16x8*)(base + (rbase + ni * 16 + l15) * 128 +
                                   (((ks * 4 + quad) ^ lb) << 4));
}

__device__ __forceinline__ void mm16(bf16x8 a[4][2], bf16x8 b[2][2],
                                     float4v acc[8][4], int mh, int nh) {
  __builtin_amdgcn_s_setprio(1);
#pragma unroll
  for (int mi = 0; mi < 4; mi++)
#pragma unroll
    for (int ni = 0; ni < 2; ni++)
#pragma unroll
      for (int ks = 0; ks < 2; ks++)
        acc[mh * 4 + mi][nh * 2 + ni] = __builtin_amdgcn_mfma_f32_16x16x32_bf16(
            a[mi][ks], b[ni][ks], acc[mh * 4 + mi][nh * 2 + ni], 0, 0, 0);
  __builtin_amdgcn_s_setprio(0);
}

__device__ __forceinline__ void gemm256_core(const u16* __restrict__ A,
                                             const u16* __restrict__ Bt, int K,
                                             int m0, int n0, float4v acc[8][4]) {
  __shared__ __align__(16) u16 L[2][2][256][64];   // 128 KiB
  int tid = threadIdx.x;
  int w = tid >> 6, lane = tid & 63;
  int l15 = lane & 15, quad = lane >> 4;
  int wm = (w >> 2) * 128, wn = (w & 3) * 64;

  // staging: wave w owns rows [w*32, w*32+32) as 4 windows of 8 rows x 64 k
  // (1KB each, coalesced). lane: local row lr=lane>>3, LDS slot sl=lane&7,
  // global chunk sl^lr (3-bit XOR; (row&7)==lr since windows are 8-aligned).
  int lr = lane >> 3, sl = lane & 7;
  const u16* pA = A + (size_t)(m0 + (w << 5) + lr) * K + ((sl ^ lr) << 3);
  const u16* pB = Bt + (size_t)(n0 + (w << 5) + lr) * K + ((sl ^ lr) << 3);
  size_t r8 = (size_t)K << 3;      // +8 rows (u16 elems)
  int dofs = (w << 11) + lane * 8; // u16 offset of window 0 dest within matrix

#define STG_A(buf, t)                                                          \
  do {                                                                         \
    const u16* s = pA + (size_t)(t) * 64;                                      \
    u16* d = &L[buf][0][0][0] + dofs;                                          \
    async16(s, d);                                                             \
    async16(s + r8, d + 512);                                                  \
    async16(s + 2 * r8, d + 1024);                                             \
    async16(s + 3 * r8, d + 1536);                                             \
  } while (0)
#define STG_B(buf, t)                                                          \
  do {                                                                         \
    const u16* s = pB + (size_t)(t) * 64;                                      \
    u16* d = &L[buf][1][0][0] + dofs;                                          \
    async16(s, d);                                                             \
    async16(s + r8, d + 512);                                                  \
    async16(s + 2 * r8, d + 1024);                                             \
    async16(s + 3 * r8, d + 1536);                                             \
  } while (0)

  // prologue: tiles 0 -> buf0, 1 -> buf1 (16 loads/thread outstanding)
  STG_A(0, 0); STG_B(0, 0);
  STG_A(1, 1); STG_B(1, 1);
  __builtin_amdgcn_s_waitcnt(WAITCNT_VM8);   // tile 0 landed; tile 1 in flight
  __builtin_amdgcn_s_barrier();

  bf16x8 a[4][2], b0[2][2], b1[2][2];
  int I = K >> 7;                            // 2 K-tiles (of 64) per iteration
  for (int i = 0; i < I; ++i) {
    int st = (i + 1 < I);
    // ================= buf0 : K-tile 2i =================
    // PH1
    ld_a4(&L[0][0][0][0], wm, quad, l15, a);
    ld_b2(&L[0][1][0][0], wn, quad, l15, b0);
    if (i > 0) STG_B(1, 2 * i + 1);          // buf1 B last read PH6 of prev iter
    __builtin_amdgcn_s_barrier();
    mm16(a, b0, acc, 0, 0);
    __builtin_amdgcn_s_barrier();
    // PH2
    ld_b2(&L[0][1][0][0], wn + 32, quad, l15, b1);
    __builtin_amdgcn_s_barrier();
    mm16(a, b1, acc, 0, 1);
    __builtin_amdgcn_s_barrier();
    // PH3
    ld_a4(&L[0][0][0][0], wm + 64, quad, l15, a);
    __builtin_amdgcn_s_barrier();
    mm16(a, b1, acc, 1, 1);
    __builtin_amdgcn_s_barrier();
    // PH4
    if (st) STG_A(0, 2 * i + 2);             // buf0 A last read PH3
    __builtin_amdgcn_s_barrier();
    mm16(a, b0, acc, 1, 0);
    if (st) __builtin_amdgcn_s_waitcnt(WAITCNT_VM4);  // tile 2i+1 fully landed
    else    __builtin_amdgcn_s_waitcnt(WAITCNT_VM0);
    __builtin_amdgcn_s_barrier();
    // ================= buf1 : K-tile 2i+1 =================
    // PH5
    ld_a4(&L[1][0][0][0], wm, quad, l15, a);
    ld_b2(&L[1][1][0][0], wn, quad, l15, b0);
    if (st) STG_B(0, 2 * i + 2);             // buf0 B last read PH2
    __builtin_amdgcn_s_barrier();
    mm16(a, b0, acc, 0, 0);
    __builtin_amdgcn_s_barrier();
    // PH6
    ld_b2(&L[1][1][0][0], wn + 32, quad, l15, b1);
    __builtin_amdgcn_s_barrier();
    mm16(a, b1, acc, 0, 1);
    __builtin_amdgcn_s_barrier();
    // PH7
    ld_a4(&L[1][0][0][0], wm + 64, quad, l15, a);
    __builtin_amdgcn_s_barrier();
    mm16(a, b1, acc, 1, 1);
    __builtin_amdgcn_s_barrier();
    // PH8
    if (st) STG_A(1, 2 * i + 3);             // buf1 A last read PH7
    __builtin_amdgcn_s_barrier();
    mm16(a, b0, acc, 1, 0);
    if (st) __builtin_amdgcn_s_waitcnt(WAITCNT_VM4);  // tile 2i+2 fully landed
    __builtin_amdgcn_s_barrier();
  }
#undef STG_A
#undef STG_B
}

// ---------------- fused QKV projection GEMM (bx-partitioned, 256^2 tiles) --
// XCD swizzle: launched index -> tile index t=(bx&7)*48+bx>>3 (384 wgs, 8 XCDs)
__global__ __launch_bounds__(512, 2) void qkv_gemm8(
    const u16* __restrict__ xbf, const u16* __restrict__ ctxbf,
    const u16* __restrict__ WqT, const u16* __restrict__ WkT, const u16* __restrict__ WvT,
    u16* __restrict__ Qb, u16* __restrict__ Kbuf, u16* __restrict__ Vtb, float qscale) {
  int bx0 = blockIdx.x;
  int bx = (bx0 & 7) * 48 + (bx0 >> 3);    // bijective: 384 = 8 x 48
  const u16* A; const u16* Bt; u16* C; int K, mode, m0, n0; float scale;
  if (bx < 256)      { int t = bx;       A = xbf;   Bt = WqT; C = Qb;   K = 1024; mode = 0; scale = qscale; m0 = (t >> 2) * 256; n0 = (t & 3) * 256; }
  else if (bx < 320) { int t = bx - 256; A = ctxbf; Bt = WkT; C = Kbuf; K = 768;  mode = 0; scale = 1.0f;   m0 = (t >> 2) * 256; n0 = (t & 3) * 256; }
  else               { int t = bx - 320; A = ctxbf; Bt = WvT; C = Vtb;  K = 768;  mode = 2; scale = 1.0f;   m0 = (t >> 2) * 256; n0 = (t & 3) * 256; }

  float4v acc[8][4] = {};
  gemm256_core(A, Bt, K, m0, n0, acc);

  int tid = threadIdx.x;
  int w = tid >> 6, lane = tid & 63;
  int l15 = lane & 15, quad = lane >> 4;
  int wm = (w >> 2) * 128, wn = (w & 3) * 64;

  if (mode == 0) {
#pragma unroll
    for (int mi = 0; mi < 8; mi++) {
      int rowb = m0 + wm + mi * 16 + quad * 4;
#pragma unroll
      for (int ni = 0; ni < 4; ni++) {
        int col = n0 + wn + ni * 16 + l15;
#pragma unroll
        for (int r = 0; r < 4; r++)
          C[(size_t)(rowb + r) * 1024 + col] = f2bf(acc[mi][ni][r] * scale);
      }
    }
  } else {
#pragma unroll
    for (int mi = 0; mi < 8; mi++) {
      int rowb = m0 + wm + mi * 16 + quad * 4;
#pragma unroll
      for (int ni = 0; ni < 4; ni++) {
        int col = n0 + wn + ni * 16 + l15;
        int hh = col >> 6, dd = col & 63;
#pragma unroll
        for (int r = 0; r < 4; r++) {
          int rr = rowb + r;
          int b = rr >> 10, skv = rr & 1023;
          _Float16 hv = (_Float16)acc[mi][ni][r];
          C[((((size_t)b * 16 + hh) * 64 + dd) << 10) + skv] = __builtin_bit_cast(u16, hv);
        }
      }
    }
  }
}

// ---------------- output projection: out = attn*WoT^T + bo (fp32, 256^2) ---
// XCD swizzle: t=(bx&7)*32+bx>>3 (256 wgs, 8 XCDs)
__global__ __launch_bounds__(512, 2) void gemm_bt8(
    const u16* __restrict__ A, const u16* __restrict__ Bt,
    float* __restrict__ C, const float* __restrict__ bias) {
  int bx0 = blockIdx.x;
  int bx = (bx0 & 7) * 32 + (bx0 >> 3);    // bijective: 256 = 8 x 32
  int m0 = (bx >> 2) * 256, n0 = (bx & 3) * 256;

  float4v acc[8][4] = {};
  gemm256_core(A, Bt, 1024, m0, n0, acc);

  int tid = threadIdx.x;
  int w = tid >> 6, lane = tid & 63;
  int l15 = lane & 15, quad = lane >> 4;
  int wm = (w >> 2) * 128, wn = (w & 3) * 64;

#pragma unroll
  for (int mi = 0; mi < 8; mi++) {
    int rowb = m0 + wm + mi * 16 + quad * 4;
#pragma unroll
    for (int ni = 0; ni < 4; ni++) {
      int col = n0 + wn + ni * 16 + l15;
      float bv = bias[col];
#pragma unroll
      for (int r = 0; r < 4; r++)
        C[(size_t)(rowb + r) * 1024 + col] = acc[mi][ni][r] + bv;
    }
  }
}

// ---------------- attention v9: per (b,h), O = softmax(Q K^T) V -------------
// grid (8, B*H) x 2 dispatches (qbase 0/8) — HALF-GRID SPLIT so the GEMMs
// surface in the top-5 profiler table. Body identical to R14/R16 v9.
// block 512 (8 waves, 32 q each), launch_bounds(512,4), KVBLK=128 (8 iters),
// 64KB LDS dbuf, XOR-swizzled.
__global__ __launch_bounds__(512, 4) void attn_kernel(
    const u16* __restrict__ Q, const u16* __restrict__ Kb,
    const u16* __restrict__ Vt, u16* __restrict__ Oout, int qbase) {
  __shared__ __align__(16) u16 lK[2][8192];   // 128kv x 64d bf16, XOR-swizzled
  __shared__ __align__(16) u16 lV[2][8192];   // 64d x 128kv f16, XOR-swizzled
  int tid = threadIdx.x, w = tid >> 6, lane = tid & 63;
  int l15 = lane & 15, quad = lane >> 4;
  int bh = blockIdx.y, b = bh >> 4, h = bh & 15;
  int q0 = (qbase + blockIdx.x) * 256 + w * 32;

  const u16* Qbase = Q + ((size_t)(b * 4096 + q0)) * 1024 + h * 64;
  const u16* Kbase = Kb + ((size_t)b << 20) + h * 64;
  const u16* Vbase = Vt + ((size_t)bh << 16);

  bf16x8 qf[2][2];
#pragma unroll
  for (int qt = 0; qt < 2; qt++)
#pragma unroll
    for (int c = 0; c < 2; c++)
      qf[qt][c] = *(const bf16x8*)(Qbase + (size_t)(qt * 16 + l15) * 1024 + c * 32 + quad * 8);

  int kr0 = tid >> 3, kx0 = ((tid & 7) ^ (kr0 & 7)) * 8;
  const u16* ks0 = Kbase + (size_t)kr0 * 1024 + kx0;
  const u16* ks1 = ks0 + (size_t)64 * 1024;
  int vd0 = tid >> 4, vc0 = ((tid & 15) ^ (vd0 & 15)) * 8;
  const u16* vs0 = Vbase + (size_t)vd0 * 1024 + vc0;
  const u16* vs1 = vs0 + (size_t)32 * 1024;
  int kdo0 = w * 512, kdo1 = 4096 + w * 512;

  async16(ks0, &lK[0][kdo0]); async16(ks1, &lK[0][kdo1]);
  async16(vs0, &lV[0][kdo0]); async16(vs1, &lV[0][kdo1]);
  ks0 += 131072; ks1 += 131072;
  vs0 += 128; vs1 += 128;

  float4v o[2][4] = {};
  float4v osum[2] = {};
  const half4 ones = {(_Float16)1.0f, (_Float16)1.0f, (_Float16)1.0f, (_Float16)1.0f};

  int lb = l15 & 7;
  int xk0 = ((0 + quad) ^ lb) * 16 + l15 * 128;
  int xk1 = ((4 + quad) ^ lb) * 16 + l15 * 128;
  int qh = quad >> 1, qo = (quad & 1) * 8;
  int vrow = l15 * 256 + qo;

  for (int it = 0; it < 8; ++it) {
    const char* bK = (const char*)lK + (it & 1) * 16384;
    const char* bV = (const char*)lV + (it & 1) * 16384;
    __syncthreads();
    if (it < 7) {
      int nb = (it + 1) & 1;
      async16(ks0, &lK[nb][kdo0]); async16(ks1, &lK[nb][kdo1]);
      async16(vs0, &lV[nb][kdo0]); async16(vs1, &lV[nb][kdo1]);
      ks0 += 131072; ks1 += 131072;
      vs0 += 128; vs1 += 128;
    }
#pragma unroll
    for (int ss = 0; ss < 8; ss++) {
      int sub = (ss + w) & 7;
      int sb = sub * 2048;
      float4v sv[2] = {{0.f, 0.f, 0.f, 0.f}, {0.f, 0.f, 0.f, 0.f}};
      __builtin_amdgcn_s_setprio(1);
#pragma unroll
      for (int c = 0; c < 2; c++) {
        bf16x8 kf = *(const bf16x8*)(bK + sb + (c ? xk1 : xk0));
#pragma unroll
        for (int qt = 0; qt < 2; qt++)
          sv[qt] = __builtin_amdgcn_mfma_f32_16x16x32_bf16(kf, qf[qt][c], sv[qt], 0, 0, 0);
      }
      __builtin_amdgcn_s_setprio(0);
      half4 pf[2];
#pragma unroll
      for (int qt = 0; qt < 2; qt++) {
        float e0 = exp2f(sv[qt][0]), e1 = exp2f(sv[qt][1]);
        float e2 = exp2f(sv[qt][2]), e3 = exp2f(sv[qt][3]);
        half2v p01 = __builtin_bit_cast(half2v, __builtin_amdgcn_cvt_pkrtz(e0, e1));
        half2v p23 = __builtin_bit_cast(half2v, __builtin_amdgcn_cvt_pkrtz(e2, e3));
        pf[qt] = __builtin_shufflevector(p01, p23, 0, 1, 2, 3);
        osum[qt] = __builtin_amdgcn_mfma_f32_16x16x16f16(ones, pf[qt], osum[qt], 0, 0, 0);
      }
      int vbs = vrow + (((sub * 2 + qh) ^ l15) * 16);
      __builtin_amdgcn_s_setprio(1);
#pragma unroll
      for (int dt = 0; dt < 4; dt++) {
        half4 vf = *(const half4*)(bV + dt * 4096 + vbs);
#pragma unroll
        for (int qt = 0; qt < 2; qt++)
          o[qt][dt] = __builtin_amdgcn_mfma_f32_16x16x16f16(vf, pf[qt], o[qt][dt], 0, 0, 0);
      }
      __builtin_amdgcn_s_setprio(0);
    }
  }

#pragma unroll
  for (int qt = 0; qt < 2; qt++) {
    float inv = 1.0f / osum[qt][0];
    u16* Ob = Oout + ((size_t)(b * 4096 + q0 + qt * 16 + l15)) * 1024 + h * 64 + quad * 4;
#pragma unroll
    for (int dt = 0; dt < 4; dt++) {
      ushort4 pk;
      pk.x = f2bf(o[qt][dt][0] * inv);
      pk.y = f2bf(o[qt][dt][1] * inv);
      pk.z = f2bf(o[qt][dt][2] * inv);
      pk.w = f2bf(o[qt][dt][3] * inv);
      *(ushort4*)(Ob + dt * 16) = pk;
    }
  }
}

// ---------------------------------------------------------------------------
extern "C" void kernel_launch(void* const* d_in, const int* in_sizes, int n_in,
                              void* d_out, int out_size, void* d_ws, size_t ws_size,
                              hipStream_t stream) {
  const float* x   = (const float*)d_in[0];
  const float* ctx = (const float*)d_in[1];
  const float* Wq  = (const float*)d_in[2];
  const float* Wk  = (const float*)d_in[3];
  const float* Wv  = (const float*)d_in[4];
  const float* Wo  = (const float*)d_in[5];
  const float* bo  = (const float*)d_in[6];
  float* out = (float*)d_out;

  u16* ws    = (u16*)d_ws;
  u16* xbf   = ws;                  // 16777216 elems (reused as attn_out)
  u16* ctxbf = xbf + 16777216;      // 3145728
  u16* WqT   = ctxbf + 3145728;     // 1048576
  u16* WkT   = WqT + 1048576;       // 786432
  u16* WvT   = WkT + 786432;        // 786432
  u16* WoT   = WvT + 786432;        // 1048576
  u16* Qb    = WoT + 1048576;       // 16777216
  u16* Kbuf  = Qb + 16777216;       // 4194304
  u16* Vtb   = Kbuf + 4194304;      // 4194304 (f16)  -> total ~93 MB
  if (ws_size < (size_t)48758784 * 2) return;  // workspace too small: clean fail

  // fused casts + weight transposes (one launch; twt blocks at grid tail)
  prep_kernel<<<23552, 256, 0, stream>>>(x, xbf, ctx, ctxbf,
                                         Wq, Wk, Wv, Wo, WqT, WkT, WvT, WoT);
  // 256 Q-blocks + 64 K-blocks + 64 V-blocks, 512 threads, 8-phase schedule
  qkv_gemm8<<<dim3(384), dim3(512), 0, stream>>>(xbf, ctxbf, WqT, WkT, WvT,
                                                 Qb, Kbuf, Vtb, 0.18033688011112042f);
  // attention -> attn_out (bf16, [b, sq, h*64+d]), reusing xbf.
  // Split into two half-grid dispatches (~58us each) for profiler visibility.
  attn_kernel<<<dim3(8, 64), dim3(512), 0, stream>>>(Qb, Kbuf, Vtb, xbf, 0);
  attn_kernel<<<dim3(8, 64), dim3(512), 0, stream>>>(Qb, Kbuf, Vtb, xbf, 8);
  // out = attn_out*Wo + bo (fp32), 64x4 tiles of 256^2
  gemm_bt8<<<dim3(256), dim3(512), 0, stream>>>(xbf, WoT, out, bo);
}

// Round 15
// 343.708 us; speedup vs baseline: 1.0351x; 1.0351x over previous
//
#include <hip/hip_runtime.h>

// ---------------------------------------------------------------------------
// CrossAttentionMM on MI355X (gfx950), bf16 MFMA pipeline.
// B=4, SQ=4096, SKV=1024, QDIM=1024, CDIM=768, H=16, D=64, INNER=1024.
// R20: R19's counters showed qkv = 73us at 14% occupancy / 26% MfmaUtil /
// 0 bank conflicts -> residency+tail bound (128KB LDS = 1 block/CU; 384
// blocks = 256+128 rounds). Core normalized-rate ~860 TF = at-ladder.
// Fix: 256x128 tiles, BK=32, dbuf 48KB LDS, acc[4][4] (~116 regs), lb(512,4)
// -> 2 blocks/CU; qkv 768 blocks full-width, bt 512 blocks fully resident.
// Cross-block TLP hides vmcnt(0) drains (m114). Chunk-XOR (4-slot, key row&3)
// on stage source + frag reads (R15-verified pattern). attn merged back to
// one dispatch (split cost 14us). prep unchanged.
// ---------------------------------------------------------------------------

typedef unsigned short u16;
typedef unsigned int u32;
typedef __bf16 bf16x8 __attribute__((ext_vector_type(8)));
typedef float float4v __attribute__((ext_vector_type(4)));
typedef _Float16 half4 __attribute__((ext_vector_type(4)));
typedef _Float16 half2v __attribute__((ext_vector_type(2)));
typedef __attribute__((address_space(1))) void as1_void;
typedef __attribute__((address_space(3))) void as3_void;

__device__ __forceinline__ u16 f2bf(float f) {
  unsigned u = __float_as_uint(f);
  u += 0x7FFF + ((u >> 16) & 1);   // RTNE
  return (u16)(u >> 16);
}

// async global->LDS, 16B per lane. LDS dest = wave-uniform base + lane*16.
__device__ __forceinline__ void async16(const u16* g, u16* l) {
  __builtin_amdgcn_global_load_lds((as1_void*)(void*)g, (as3_void*)l, 16, 0, 0);
}

// gfx9 waitcnt imm: vmcnt[3:0]=imm[3:0], exp=imm[6:4], lgkm=imm[11:8], vmcnt[5:4]=imm[15:14]
#define WAITCNT_VM0 0xF70   // vmcnt(0), lgkm/exp no-wait

// ---------------- fused prep: fp32->bf16 casts + all 4 weight transposes ---
__global__ void prep_kernel(const float* __restrict__ x, u16* __restrict__ xbf,
                            const float* __restrict__ ctx, u16* __restrict__ ctxbf,
                            const float* __restrict__ Wq, const float* __restrict__ Wk,
                            const float* __restrict__ Wv, const float* __restrict__ Wo,
                            u16* __restrict__ WqT, u16* __restrict__ WkT,
                            u16* __restrict__ WvT, u16* __restrict__ WoT) {
  __shared__ u16 t[32][33];
  int blk = blockIdx.x;
  if (blk < 19456) {
    int i = blk * 256 + threadIdx.x;
    const float* in; u16* out; int j;
    if (i < 4194304) { in = x; out = xbf; j = i; }
    else if (i < 4980736) { in = ctx; out = ctxbf; j = i - 4194304; }
    else return;
    float4 v = ((const float4*)in)[j];
    ushort4 o;
    o.x = f2bf(v.x); o.y = f2bf(v.y); o.z = f2bf(v.z); o.w = f2bf(v.w);
    ((ushort4*)out)[j] = o;
    return;
  }
  int rem = blk - 19456;
  int z = rem >> 10, r1 = rem & 1023;
  int by = r1 >> 5, bxx = r1 & 31;
  const float* W = z == 0 ? Wq : z == 1 ? Wk : z == 2 ? Wv : Wo;
  u16* Wt = z == 0 ? WqT : z == 1 ? WkT : z == 2 ? WvT : WoT;
  int Kd = (z == 1 || z == 2) ? 768 : 1024;
  int k0 = by * 32;
  if (k0 >= Kd) return;
  int tid = threadIdx.x;
  int tx = tid & 31, ty = tid >> 5;
  int n0 = bxx * 32;
#pragma unroll
  for (int i = 0; i < 4; i++)
    t[ty + i * 8][tx] = f2bf(W[(size_t)(k0 + ty + i * 8) * 1024 + n0 + tx]);
  __syncthreads();
#pragma unroll
  for (int i = 0; i < 4; i++)
    Wt[(size_t)(n0 + ty + i * 8) * Kd + k0 + tx] = t[tx][ty + i * 8];
}

// ---------------------------------------------------------------------------
// 256x128 / BK=32 GEMM core (C = A * Bt^T), bf16. 512 thr = 8 waves (4m x 2n),
// per-wave 64x64 out = acc[4][4]. Double-buffered 48KB LDS:
// [buf][A: 256 rows x 32k | B: 128 rows x 32k], 4-slot chunk-XOR (key row&3).
// Stage 3x async16/thread per K-tile; vmcnt(0)+1 barrier per K-tile; 2 blocks
// per CU cover the drains (m114).
// ---------------------------------------------------------------------------
__device__ __forceinline__ void gemm_h_core(const u16* __restrict__ A,
                                            const u16* __restrict__ Bt, int K,
                                            int m0, int n0, float4v acc[4][4]) {
  __shared__ __align__(16) u16 L[2][12288];   // 48 KiB
  int tid = threadIdx.x;
  int w = tid >> 6, lane = tid & 63;
  int l15 = lane & 15, quad = lane >> 4;
  int wm = (w >> 1) * 64, wn = (w & 1) * 64;

  // staging: thread t covers chunks {t, t+512 (A rows+128), t+1024 (B)}.
  // chunk -> row r=c>>2, LDS slot s=c&3, global k-chunk s^(r&3).
  int r0 = tid >> 2, s0 = tid & 3;
  int gx = (s0 ^ (r0 & 3)) << 3;               // global k offset (u16)
  const u16* pA0 = A + (size_t)(m0 + r0) * K + gx;
  const u16* pA1 = pA0 + (size_t)128 * K;      // rows+128: (r&3) unchanged
  const u16* pB  = Bt + (size_t)(n0 + r0) * K + gx;
  int dofs = tid * 8;

#define STG(buf, t)                                                            \
  do {                                                                         \
    async16(pA0 + (size_t)(t) * 32, &L[buf][dofs]);                            \
    async16(pA1 + (size_t)(t) * 32, &L[buf][4096 + dofs]);                     \
    async16(pB + (size_t)(t) * 32, &L[buf][8192 + dofs]);                      \
  } while (0)

  STG(0, 0);
  int niter = K >> 5;
  int cur = 0;
  int lb2 = l15 & 3;
  for (int it = 0; it < niter; ++it) {
    __builtin_amdgcn_s_waitcnt(WAITCNT_VM0);   // buf[cur] landed
    __builtin_amdgcn_s_barrier();              // all waves past buf[cur^1] reads
    if (it + 1 < niter) STG(cur ^ 1, it + 1);
    const u16* Lb = &L[cur][0];
    bf16x8 fa[4], fb[4];
#pragma unroll
    for (int mi = 0; mi < 4; mi++)
      fa[mi] = *(const bf16x8*)&Lb[(wm + mi * 16 + l15) * 32 + ((quad ^ lb2) << 3)];
#pragma unroll
    for (int ni = 0; ni < 4; ni++)
      fb[ni] = *(const bf16x8*)&Lb[8192 + (wn + ni * 16 + l15) * 32 + ((quad ^ lb2) << 3)];
    __builtin_amdgcn_s_setprio(1);
#pragma unroll
    for (int mi = 0; mi < 4; mi++)
#pragma unroll
      for (int ni = 0; ni < 4; ni++)
        acc[mi][ni] = __builtin_amdgcn_mfma_f32_16x16x32_bf16(fa[mi], fb[ni], acc[mi][ni], 0, 0, 0);
    __builtin_amdgcn_s_setprio(0);
    cur ^= 1;
  }
#undef STG
}

// ---------------- fused QKV projection GEMM (256x128 tiles) ----------------
// t<512:    Q = xbf*WqT   (64 m x 8 n), K=1024, bf16 out, qk-scale folded
// 512..639: K = ctxbf*WkT (16 m x 8 n), K=768, bf16 out
// 640..767: V = ctxbf*WvT (16 m x 8 n), K=768 -> Vt[b,h,d,skv] f16 scatter
// XCD swizzle: bx=(bx0&7)*96+bx0>>3 (768 = 8 x 96, bijective)
__global__ __launch_bounds__(512, 4) void qkv_gemm_h(
    const u16* __restrict__ xbf, const u16* __restrict__ ctxbf,
    const u16* __restrict__ WqT, const u16* __restrict__ WkT, const u16* __restrict__ WvT,
    u16* __restrict__ Qb, u16* __restrict__ Kbuf, u16* __restrict__ Vtb, float qscale) {
  int bx0 = blockIdx.x;
  int bx = (bx0 & 7) * 96 + (bx0 >> 3);
  const u16* A; const u16* Bt; u16* C; int K, mode, m0, n0; float scale;
  if (bx < 512)      { int t = bx;       A = xbf;   Bt = WqT; C = Qb;   K = 1024; mode = 0; scale = qscale; m0 = (t >> 3) * 256; n0 = (t & 7) * 128; }
  else if (bx < 640) { int t = bx - 512; A = ctxbf; Bt = WkT; C = Kbuf; K = 768;  mode = 0; scale = 1.0f;   m0 = (t >> 3) * 256; n0 = (t & 7) * 128; }
  else               { int t = bx - 640; A = ctxbf; Bt = WvT; C = Vtb;  K = 768;  mode = 2; scale = 1.0f;   m0 = (t >> 3) * 256; n0 = (t & 7) * 128; }

  float4v acc[4][4] = {};
  gemm_h_core(A, Bt, K, m0, n0, acc);

  int tid = threadIdx.x;
  int w = tid >> 6, lane = tid & 63;
  int l15 = lane & 15, quad = lane >> 4;
  int wm = (w >> 1) * 64, wn = (w & 1) * 64;

  if (mode == 0) {
#pragma unroll
    for (int mi = 0; mi < 4; mi++) {
      int rowb = m0 + wm + mi * 16 + quad * 4;
#pragma unroll
      for (int ni = 0; ni < 4; ni++) {
        int col = n0 + wn + ni * 16 + l15;
#pragma unroll
        for (int r = 0; r < 4; r++)
          C[(size_t)(rowb + r) * 1024 + col] = f2bf(acc[mi][ni][r] * scale);
      }
    }
  } else {
#pragma unroll
    for (int mi = 0; mi < 4; mi++) {
      int rowb = m0 + wm + mi * 16 + quad * 4;
#pragma unroll
      for (int ni = 0; ni < 4; ni++) {
        int col = n0 + wn + ni * 16 + l15;
        int hh = col >> 6, dd = col & 63;
#pragma unroll
        for (int r = 0; r < 4; r++) {
          int rr = rowb + r;
          int b = rr >> 10, skv = rr & 1023;
          _Float16 hv = (_Float16)acc[mi][ni][r];
          C[((((size_t)b * 16 + hh) * 64 + dd) << 10) + skv] = __builtin_bit_cast(u16, hv);
        }
      }
    }
  }
}

// ---------------- output projection: out = attn*WoT^T + bo (fp32) ----------
// 512 blocks (64 m x 8 n) -> fully resident at 2 blocks/CU, single round.
// XCD swizzle: bx=(bx0&7)*64+bx0>>3 (512 = 8 x 64, bijective)
__global__ __launch_bounds__(512, 4) void gemm_bt_h(
    const u16* __restrict__ A, const u16* __restrict__ Bt,
    float* __restrict__ C, const float* __restrict__ bias) {
  int bx0 = blockIdx.x;
  int bx = (bx0 & 7) * 64 + (bx0 >> 3);
  int m0 = (bx >> 3) * 256, n0 = (bx & 7) * 128;

  float4v acc[4][4] = {};
  gemm_h_core(A, Bt, 1024, m0, n0, acc);

  int tid = threadIdx.x;
  int w = tid >> 6, lane = tid & 63;
  int l15 = lane & 15, quad = lane >> 4;
  int wm = (w >> 1) * 64, wn = (w & 1) * 64;

#pragma unroll
  for (int mi = 0; mi < 4; mi++) {
    int rowb = m0 + wm + mi * 16 + quad * 4;
#pragma unroll
    for (int ni = 0; ni < 4; ni++) {
      int col = n0 + wn + ni * 16 + l15;
      float bv = bias[col];
#pragma unroll
      for (int r = 0; r < 4; r++)
        C[(size_t)(rowb + r) * 1024 + col] = acc[mi][ni][r] + bv;
    }
  }
}

// ---------------- attention v9: per (b,h), O = softmax(Q K^T) V -------------
// grid (SQ/256, B*H) single dispatch, block 512 (8 waves, 32 q each),
// launch_bounds(512,4). KVBLK=128 (8 iters), 64KB LDS dbuf, XOR-swizzled.
__global__ __launch_bounds__(512, 4) void attn_kernel(
    const u16* __restrict__ Q, const u16* __restrict__ Kb,
    const u16* __restrict__ Vt, u16* __restrict__ Oout) {
  __shared__ __align__(16) u16 lK[2][8192];   // 128kv x 64d bf16, XOR-swizzled
  __shared__ __align__(16) u16 lV[2][8192];   // 64d x 128kv f16, XOR-swizzled
  int tid = threadIdx.x, w = tid >> 6, lane = tid & 63;
  int l15 = lane & 15, quad = lane >> 4;
  int bh = blockIdx.y, b = bh >> 4, h = bh & 15;
  int q0 = blockIdx.x * 256 + w * 32;

  const u16* Qbase = Q + ((size_t)(b * 4096 + q0)) * 1024 + h * 64;
  const u16* Kbase = Kb + ((size_t)b << 20) + h * 64;
  const u16* Vbase = Vt + ((size_t)bh << 16);

  bf16x8 qf[2][2];
#pragma unroll
  for (int qt = 0; qt < 2; qt++)
#pragma unroll
    for (int c = 0; c < 2; c++)
      qf[qt][c] = *(const bf16x8*)(Qbase + (size_t)(qt * 16 + l15) * 1024 + c * 32 + quad * 8);

  int kr0 = tid >> 3, kx0 = ((tid & 7) ^ (kr0 & 7)) * 8;
  const u16* ks0 = Kbase + (size_t)kr0 * 1024 + kx0;
  const u16* ks1 = ks0 + (size_t)64 * 1024;
  int vd0 = tid >> 4, vc0 = ((tid & 15) ^ (vd0 & 15)) * 8;
  const u16* vs0 = Vbase + (size_t)vd0 * 1024 + vc0;
  const u16* vs1 = vs0 + (size_t)32 * 1024;
  int kdo0 = w * 512, kdo1 = 4096 + w * 512;

  async16(ks0, &lK[0][kdo0]); async16(ks1, &lK[0][kdo1]);
  async16(vs0, &lV[0][kdo0]); async16(vs1, &lV[0][kdo1]);
  ks0 += 131072; ks1 += 131072;
  vs0 += 128; vs1 += 128;

  float4v o[2][4] = {};
  float4v osum[2] = {};
  const half4 ones = {(_Float16)1.0f, (_Float16)1.0f, (_Float16)1.0f, (_Float16)1.0f};

  int lb = l15 & 7;
  int xk0 = ((0 + quad) ^ lb) * 16 + l15 * 128;
  int xk1 = ((4 + quad) ^ lb) * 16 + l15 * 128;
  int qh = quad >> 1, qo = (quad & 1) * 8;
  int vrow = l15 * 256 + qo;

  for (int it = 0; it < 8; ++it) {
    const char* bK = (const char*)lK + (it & 1) * 16384;
    const char* bV = (const char*)lV + (it & 1) * 16384;
    __syncthreads();
    if (it < 7) {
      int nb = (it + 1) & 1;
      async16(ks0, &lK[nb][kdo0]); async16(ks1, &lK[nb][kdo1]);
      async16(vs0, &lV[nb][kdo0]); async16(vs1, &lV[nb][kdo1]);
      ks0 += 131072; ks1 += 131072;
      vs0 += 128; vs1 += 128;
    }
#pragma unroll
    for (int ss = 0; ss < 8; ss++) {
      int sub = (ss + w) & 7;
      int sb = sub * 2048;
      float4v sv[2] = {{0.f, 0.f, 0.f, 0.f}, {0.f, 0.f, 0.f, 0.f}};
      __builtin_amdgcn_s_setprio(1);
#pragma unroll
      for (int c = 0; c < 2; c++) {
        bf16x8 kf = *(const bf16x8*)(bK + sb + (c ? xk1 : xk0));
#pragma unroll
        for (int qt = 0; qt < 2; qt++)
          sv[qt] = __builtin_amdgcn_mfma_f32_16x16x32_bf16(kf, qf[qt][c], sv[qt], 0, 0, 0);
      }
      __builtin_amdgcn_s_setprio(0);
      half4 pf[2];
#pragma unroll
      for (int qt = 0; qt < 2; qt++) {
        float e0 = exp2f(sv[qt][0]), e1 = exp2f(sv[qt][1]);
        float e2 = exp2f(sv[qt][2]), e3 = exp2f(sv[qt][3]);
        half2v p01 = __builtin_bit_cast(half2v, __builtin_amdgcn_cvt_pkrtz(e0, e1));
        half2v p23 = __builtin_bit_cast(half2v, __builtin_amdgcn_cvt_pkrtz(e2, e3));
        pf[qt] = __builtin_shufflevector(p01, p23, 0, 1, 2, 3);
        osum[qt] = __builtin_amdgcn_mfma_f32_16x16x16f16(ones, pf[qt], osum[qt], 0, 0, 0);
      }
      int vbs = vrow + (((sub * 2 + qh) ^ l15) * 16);
      __builtin_amdgcn_s_setprio(1);
#pragma unroll
      for (int dt = 0; dt < 4; dt++) {
        half4 vf = *(const half4*)(bV + dt * 4096 + vbs);
#pragma unroll
        for (int qt = 0; qt < 2; qt++)
          o[qt][dt] = __builtin_amdgcn_mfma_f32_16x16x16f16(vf, pf[qt], o[qt][dt], 0, 0, 0);
      }
      __builtin_amdgcn_s_setprio(0);
    }
  }

#pragma unroll
  for (int qt = 0; qt < 2; qt++) {
    float inv = 1.0f / osum[qt][0];
    u16* Ob = Oout + ((size_t)(b * 4096 + q0 + qt * 16 + l15)) * 1024 + h * 64 + quad * 4;
#pragma unroll
    for (int dt = 0; dt < 4; dt++) {
      ushort4 pk;
      pk.x = f2bf(o[qt][dt][0] * inv);
      pk.y = f2bf(o[qt][dt][1] * inv);
      pk.z = f2bf(o[qt][dt][2] * inv);
      pk.w = f2bf(o[qt][dt][3] * inv);
      *(ushort4*)(Ob + dt * 16) = pk;
    }
  }
}

// ---------------------------------------------------------------------------
extern "C" void kernel_launch(void* const* d_in, const int* in_sizes, int n_in,
                              void* d_out, int out_size, void* d_ws, size_t ws_size,
                              hipStream_t stream) {
  const float* x   = (const float*)d_in[0];
  const float* ctx = (const float*)d_in[1];
  const float* Wq  = (const float*)d_in[2];
  const float* Wk  = (const float*)d_in[3];
  const float* Wv  = (const float*)d_in[4];
  const float* Wo  = (const float*)d_in[5];
  const float* bo  = (const float*)d_in[6];
  float* out = (float*)d_out;

  u16* ws    = (u16*)d_ws;
  u16* xbf   = ws;                  // 16777216 elems (reused as attn_out)
  u16* ctxbf = xbf + 16777216;      // 3145728
  u16* WqT   = ctxbf + 3145728;     // 1048576
  u16* WkT   = WqT + 1048576;       // 786432
  u16* WvT   = WkT + 786432;        // 786432
  u16* WoT   = WvT + 786432;        // 1048576
  u16* Qb    = WoT + 1048576;       // 16777216
  u16* Kbuf  = Qb + 16777216;       // 4194304
  u16* Vtb   = Kbuf + 4194304;      // 4194304 (f16)  -> total ~93 MB
  if (ws_size < (size_t)48758784 * 2) return;  // workspace too small: clean fail

  // fused casts + weight transposes
  prep_kernel<<<23552, 256, 0, stream>>>(x, xbf, ctx, ctxbf,
                                         Wq, Wk, Wv, Wo, WqT, WkT, WvT, WoT);
  // Q (512) + K (128) + V (128) tiles of 256x128, 2 blocks/CU
  qkv_gemm_h<<<dim3(768), dim3(512), 0, stream>>>(xbf, ctxbf, WqT, WkT, WvT,
                                                  Qb, Kbuf, Vtb, 0.18033688011112042f);
  // attention -> attn_out (bf16, [b, sq, h*64+d]), reusing xbf (single dispatch)
  attn_kernel<<<dim3(16, 64), dim3(512), 0, stream>>>(Qb, Kbuf, Vtb, xbf);
  // out = attn_out*Wo + bo (fp32), 512 tiles of 256x128, fully resident
  gemm_bt_h<<<dim3(512), dim3(512), 0, stream>>>(xbf, WoT, out, bo);
}